// Round 1
// baseline (1283.622 us; speedup 1.0000x reference)
//
#include <hip/hip_runtime.h>
#include <stdint.h>

// ---------------------------------------------------------------------------
// SpatialAggregator: axial attention, B=8 C=512 H=W=64, DEPTH=4, HEADS=8
// Staged pipeline, bf16 MFMA (16x16x32), fp32 accumulate.
// ---------------------------------------------------------------------------

typedef __attribute__((ext_vector_type(8))) short bf16x8;
typedef __attribute__((ext_vector_type(4))) float f32x4;
typedef unsigned short u16;
typedef unsigned int u32;

#define MFMA16(a, b, c) __builtin_amdgcn_mfma_f32_16x16x32_bf16((a), (b), (c), 0, 0, 0)

__device__ __forceinline__ float b2f(u16 h) {
    u32 u = ((u32)h) << 16;
    float f;
    __builtin_memcpy(&f, &u, 4);
    return f;
}
__device__ __forceinline__ u16 f2b(float f) {
    u32 u;
    __builtin_memcpy(&u, &f, 4);
    u32 r = (u + 0x7fffu + ((u >> 16) & 1u)) >> 16;   // RNE
    return (u16)r;
}

#define GLD_LDS16(g, l)                                                        \
    __builtin_amdgcn_global_load_lds(                                          \
        (const __attribute__((address_space(1))) void*)(g),                    \
        (__attribute__((address_space(3))) void*)(l), 16, 0, 0)

// ---------------------------------------------------------------------------
// embed: x (B,C,H,W) f32 + pos_h (C,H) + pos_w (C,W) -> y (B,H,W,C) bf16
// block: 64c x 64w tile at (b, h).  grid (8 cblk, 64 h, 8 b), 256 thr.
// ---------------------------------------------------------------------------
__global__ __launch_bounds__(256) void embed_kernel(
    const float* __restrict__ x, const float* __restrict__ ph,
    const float* __restrict__ pw, u16* __restrict__ y)
{
    __shared__ float tile[64][65];
    const int c0 = blockIdx.x * 64, h = blockIdx.y, b = blockIdx.z;
    const int t = threadIdx.x;
#pragma unroll
    for (int i = 0; i < 4; ++i) {
        int cl = (t >> 4) + i * 16;
        int w4 = (t & 15) * 4;
        const float* src = x + (((size_t)(b * 512 + c0 + cl)) * 64 + h) * 64 + w4;
        float4 v = *(const float4*)src;
        float p = ph[(c0 + cl) * 64 + h];
        tile[cl][w4 + 0] = v.x + p + pw[(c0 + cl) * 64 + w4 + 0];
        tile[cl][w4 + 1] = v.y + p + pw[(c0 + cl) * 64 + w4 + 1];
        tile[cl][w4 + 2] = v.z + p + pw[(c0 + cl) * 64 + w4 + 2];
        tile[cl][w4 + 3] = v.w + p + pw[(c0 + cl) * 64 + w4 + 3];
    }
    __syncthreads();
    const int wl = t >> 2, cb = (t & 3) * 16;
    bf16x8 o0, o1;
#pragma unroll
    for (int j = 0; j < 8; ++j) o0[j] = (short)f2b(tile[cb + j][wl]);
#pragma unroll
    for (int j = 0; j < 8; ++j) o1[j] = (short)f2b(tile[cb + 8 + j][wl]);
    u16* dst = y + (((size_t)(b * 64 + h) * 64 + wl) * 512 + c0 + cb);
    *(bf16x8*)dst = o0;
    *(bf16x8*)(dst + 8) = o1;
}

// ---------------------------------------------------------------------------
// weight transpose: W[k][n] f32 -> WT[n][k] bf16, all 24 matrices.
// wT layout per (l,axis): [ qT 512x512 | kvT 1024x512 | woT 512x512 ], ld=512
// grid (8 kblk, 16 nblk, 24), 256 thr.
// ---------------------------------------------------------------------------
__global__ __launch_bounds__(256) void wtrans_kernel(
    const float* __restrict__ wq, const float* __restrict__ wkv,
    const float* __restrict__ wo, u16* __restrict__ wT)
{
    const int mid = blockIdx.z;
    const int l = mid / 6, rest = mid % 6, axis = rest / 3, which = rest % 3;
    const size_t la = (size_t)(l * 2 + axis);
    const float* src;
    int N;
    size_t doff;
    if (which == 0)      { src = wq  + la * 512 * 512;  N = 512;  doff = la * (2048 * 512); }
    else if (which == 1) { src = wkv + la * 512 * 1024; N = 1024; doff = la * (2048 * 512) + 512 * 512; }
    else                 { src = wo  + la * 512 * 512;  N = 512;  doff = la * (2048 * 512) + 512 * 512 + 1024 * 512; }
    const int n0 = blockIdx.y * 64;
    if (n0 >= N) return;
    const int k0 = blockIdx.x * 64;
    __shared__ float tile[64][65];
    const int t = threadIdx.x;
#pragma unroll
    for (int i = 0; i < 4; ++i) {
        int kl = (t >> 4) + i * 16;
        int n4 = (t & 15) * 4;
        float4 v = *(const float4*)(src + (size_t)(k0 + kl) * N + n0 + n4);
        tile[kl][n4 + 0] = v.x; tile[kl][n4 + 1] = v.y;
        tile[kl][n4 + 2] = v.z; tile[kl][n4 + 3] = v.w;
    }
    __syncthreads();
    const int nl = t >> 2, kb = (t & 3) * 16;
    bf16x8 o0, o1;
#pragma unroll
    for (int j = 0; j < 8; ++j) o0[j] = (short)f2b(tile[kb + j][nl]);
#pragma unroll
    for (int j = 0; j < 8; ++j) o1[j] = (short)f2b(tile[kb + 8 + j][nl]);
    u16* dst = wT + doff + (size_t)(n0 + nl) * 512 + k0 + kb;
    *(bf16x8*)dst = o0;
    *(bf16x8*)(dst + 8) = o1;
}

// ---------------------------------------------------------------------------
// GEMM: C[M=32768, N] = A[M,512] * WT[N,512]^T (+bias) (+in-place add) -> bf16
// 128x128 tile, BK=64, 4 waves of 64x64, mfma 16x16x32 bf16.
// LDS XOR-swizzle (chunk ^= row&7) with pre-swizzled global source so
// global_load_lds stays linear.  MODE: 0=plain, 1=+bias, 2=+bias+inplace add.
// ---------------------------------------------------------------------------
template <int MODE>
__global__ __launch_bounds__(256) void gemm_bt(
    const u16* __restrict__ A, int lda,
    const u16* __restrict__ Bt,
    const float* __restrict__ bias,
    u16* C, int ldc)
{
    __shared__ u16 As[128 * 64];
    __shared__ u16 Bs[128 * 64];
    const int tid = threadIdx.x;
    const int lane = tid & 63;
    const int wv = tid >> 6;
    const int wr = (wv >> 1) * 64, wc = (wv & 1) * 64;
    const int m0 = blockIdx.x * 128;
    const int n0 = blockIdx.y * 128;
    const int rl = lane >> 3;    // row within 8-row staging group
    const int cp = lane & 7;     // physical 16B chunk
    const int l16 = lane & 15;
    const int kgrp = (lane >> 4) << 3;   // k element offset 0/8/16/24
    f32x4 acc[4][4] = {};

    for (int ks = 0; ks < 512; ks += 64) {
#pragma unroll
        for (int i = 0; i < 4; ++i) {
            int row = wv * 8 + i * 32 + rl;
            int clog = cp ^ (row & 7);
            const u16* src = A + (size_t)(m0 + row) * lda + ks + clog * 8;
            GLD_LDS16(src, As + (wv * 8 + i * 32) * 64);
        }
#pragma unroll
        for (int i = 0; i < 4; ++i) {
            int row = wv * 8 + i * 32 + rl;
            int clog = cp ^ (row & 7);
            const u16* src = Bt + (size_t)(n0 + row) * 512 + ks + clog * 8;
            GLD_LDS16(src, Bs + (wv * 8 + i * 32) * 64);
        }
        __syncthreads();
#pragma unroll
        for (int kk = 0; kk < 2; ++kk) {
            bf16x8 af[4], bfr[4];
            const int kb = (kk * 32 + kgrp) * 2;
#pragma unroll
            for (int mf = 0; mf < 4; ++mf) {
                int row = wr + mf * 16 + l16;
                af[mf] = *(const bf16x8*)((const char*)As + row * 128 + (kb ^ ((row & 7) << 4)));
            }
#pragma unroll
            for (int nf = 0; nf < 4; ++nf) {
                int row = wc + nf * 16 + l16;
                bfr[nf] = *(const bf16x8*)((const char*)Bs + row * 128 + (kb ^ ((row & 7) << 4)));
            }
#pragma unroll
            for (int mf = 0; mf < 4; ++mf)
#pragma unroll
                for (int nf = 0; nf < 4; ++nf)
                    acc[mf][nf] = MFMA16(af[mf], bfr[nf], acc[mf][nf]);
        }
        __syncthreads();
    }

    float bv[4];
    if (MODE >= 1) {
#pragma unroll
        for (int nf = 0; nf < 4; ++nf) bv[nf] = bias[n0 + wc + nf * 16 + l16];
    }
#pragma unroll
    for (int mf = 0; mf < 4; ++mf) {
#pragma unroll
        for (int r = 0; r < 4; ++r) {
            int m = m0 + wr + mf * 16 + ((lane >> 4) << 2) + r;
#pragma unroll
            for (int nf = 0; nf < 4; ++nf) {
                int n = n0 + wc + nf * 16 + l16;
                float v = acc[mf][nf][r];
                if (MODE >= 1) v += bv[nf];
                if (MODE == 2) v += b2f(C[(size_t)m * ldc + n]);  // oh accumulate
                C[(size_t)m * ldc + n] = f2b(v);
            }
        }
    }
}

// ---------------------------------------------------------------------------
// attention: per sequence of 64 tokens, 8 heads.  QKV rows = [q|k|v] (1536).
// One block = one sequence; 4 waves x 2 heads each.  Q in regs, K/V in LDS
// (XOR-swizzled), full softmax (L=64), P through LDS, output written back
// into the Q slots (aliasing is safe: each block reads only its own rows).
// ---------------------------------------------------------------------------
__global__ __launch_bounds__(256) void attn_kernel(u16* QKV, int bstr, int tstr)
{
    __shared__ u16 sm[4][2][64 * 64];   // per wave: [0]=K then P, [1]=V^T
    const int bi = blockIdx.x;
    const int base = (bi >> 6) * 4096 + (bi & 63) * bstr;
    const int tid = threadIdx.x, lane = tid & 63, wv = tid >> 6;
    const int l16 = lane & 15, kgrp = (lane >> 4) << 3;
    const int rl = lane >> 3, cp = lane & 7;
    u16* Kl = (u16*)sm[wv][0];
    u16* Vt = (u16*)sm[wv][1];

    for (int hh = 0; hh < 2; ++hh) {
        const int head = wv + hh * 4;
        const int hoff = head * 64;

        // Q fragments (A-operand): row = token, k = e
        bf16x8 q[4][2];
#pragma unroll
        for (int mf = 0; mf < 4; ++mf)
#pragma unroll
            for (int k2 = 0; k2 < 2; ++k2) {
                const u16* p = QKV + (size_t)(base + (mf * 16 + l16) * tstr) * 1536
                             + hoff + k2 * 32 + kgrp;
                q[mf][k2] = *(const bf16x8*)p;
            }
        // V rows into regs (for transposed LDS store later)
        bf16x8 vvr[8];
#pragma unroll
        for (int i = 0; i < 8; ++i) {
            int j = i * 8 + rl;
            vvr[i] = *(const bf16x8*)(QKV + (size_t)(base + j * tstr) * 1536 + 1024 + hoff + cp * 8);
        }
        // K stage -> LDS (pre-swizzled source, linear dest)
#pragma unroll
        for (int i = 0; i < 8; ++i) {
            int row = i * 8 + rl;
            int clog = cp ^ (row & 7);
            const u16* src = QKV + (size_t)(base + row * tstr) * 1536 + 512 + hoff + clog * 8;
            GLD_LDS16(src, Kl + i * 8 * 64);
        }
        __syncthreads();   // drains vmcnt: K visible

        // dots = Q K^T   (B-operand rows = K rows)
        f32x4 dt[4][4] = {};
#pragma unroll
        for (int k2 = 0; k2 < 2; ++k2) {
            bf16x8 bfr[4];
            const int kb = (k2 * 32 + kgrp) * 2;
#pragma unroll
            for (int jf = 0; jf < 4; ++jf) {
                int row = jf * 16 + l16;
                bfr[jf] = *(const bf16x8*)((const char*)Kl + row * 128 + (kb ^ ((row & 7) << 4)));
            }
#pragma unroll
            for (int mf = 0; mf < 4; ++mf)
#pragma unroll
                for (int jf = 0; jf < 4; ++jf)
                    dt[mf][jf] = MFMA16(q[mf][k2], bfr[jf], dt[mf][jf]);
        }

        // softmax over j (row i = mf*16 + (lane>>4)*4 + r; cols j = jf*16 + lane%16)
#pragma unroll
        for (int mf = 0; mf < 4; ++mf) {
#pragma unroll
            for (int r = 0; r < 4; ++r) {
                float a0 = dt[mf][0][r] * 0.125f, a1 = dt[mf][1][r] * 0.125f;
                float a2 = dt[mf][2][r] * 0.125f, a3 = dt[mf][3][r] * 0.125f;
                float mx = fmaxf(fmaxf(a0, a1), fmaxf(a2, a3));
#pragma unroll
                for (int msk = 1; msk < 16; msk <<= 1) mx = fmaxf(mx, __shfl_xor(mx, msk, 64));
                float e0 = __expf(a0 - mx), e1 = __expf(a1 - mx);
                float e2 = __expf(a2 - mx), e3 = __expf(a3 - mx);
                float sum = e0 + e1 + e2 + e3;
#pragma unroll
                for (int msk = 1; msk < 16; msk <<= 1) sum += __shfl_xor(sum, msk, 64);
                float inv = __builtin_amdgcn_rcpf(sum);
                dt[mf][0][r] = e0 * inv; dt[mf][1][r] = e1 * inv;
                dt[mf][2][r] = e2 * inv; dt[mf][3][r] = e3 * inv;
            }
        }

        // V^T into LDS (swizzled), from regs
#pragma unroll
        for (int i = 0; i < 8; ++i) {
            int j = i * 8 + rl;
#pragma unroll
            for (int t = 0; t < 8; ++t) {
                int e = cp * 8 + t;
                int addr = e * 128 + 2 * j;
                *(u16*)((char*)Vt + (addr ^ ((e & 7) << 4))) = (u16)vvr[i][t];
            }
        }
        // P into LDS (reuses K region; per-wave LDS ordering keeps this safe)
#pragma unroll
        for (int mf = 0; mf < 4; ++mf)
#pragma unroll
            for (int r = 0; r < 4; ++r) {
                int irow = mf * 16 + ((lane >> 4) << 2) + r;
#pragma unroll
                for (int jf = 0; jf < 4; ++jf) {
                    int j = jf * 16 + l16;
                    int addr = irow * 128 + 2 * j;
                    *(u16*)((char*)Kl + (addr ^ ((irow & 7) << 4))) = f2b(dt[mf][jf][r]);
                }
            }

        // out = P V
        f32x4 o[4][4] = {};
#pragma unroll
        for (int k2 = 0; k2 < 2; ++k2) {
            bf16x8 af[4], bfr[4];
            const int kb = (k2 * 32 + kgrp) * 2;
#pragma unroll
            for (int mf = 0; mf < 4; ++mf) {
                int row = mf * 16 + l16;
                af[mf] = *(const bf16x8*)((const char*)Kl + row * 128 + (kb ^ ((row & 7) << 4)));
            }
#pragma unroll
            for (int ef = 0; ef < 4; ++ef) {
                int row = ef * 16 + l16;
                bfr[ef] = *(const bf16x8*)((const char*)Vt + row * 128 + (kb ^ ((row & 7) << 4)));
            }
#pragma unroll
            for (int mf = 0; mf < 4; ++mf)
#pragma unroll
                for (int ef = 0; ef < 4; ++ef)
                    o[mf][ef] = MFMA16(af[mf], bfr[ef], o[mf][ef]);
        }

        // write attention output into the Q slots (cols head*64 + e)
#pragma unroll
        for (int mf = 0; mf < 4; ++mf)
#pragma unroll
            for (int r = 0; r < 4; ++r) {
                int irow = mf * 16 + ((lane >> 4) << 2) + r;
                size_t rowoff = (size_t)(base + irow * tstr) * 1536;
#pragma unroll
                for (int ef = 0; ef < 4; ++ef) {
                    int e = ef * 16 + l16;
                    QKV[rowoff + hoff + e] = f2b(o[mf][ef][r]);
                }
            }
        __syncthreads();   // all LDS traffic done before next head reuses regions
    }
}

// ---------------------------------------------------------------------------
// final: y (B,H,W,C) bf16 -> out (B,C,H,W) f32
// ---------------------------------------------------------------------------
__global__ __launch_bounds__(256) void untrans_kernel(
    const u16* __restrict__ y, float* __restrict__ out)
{
    __shared__ float tile[64][65];   // [w][c]
    const int c0 = blockIdx.x * 64, h = blockIdx.y, b = blockIdx.z;
    const int t = threadIdx.x;
    {
        const int wl = t >> 2, cb = (t & 3) * 16;
        const u16* src = y + (((size_t)(b * 64 + h) * 64 + wl) * 512 + c0 + cb);
        bf16x8 v0 = *(const bf16x8*)src;
        bf16x8 v1 = *(const bf16x8*)(src + 8);
#pragma unroll
        for (int j = 0; j < 8; ++j) tile[wl][cb + j] = b2f((u16)v0[j]);
#pragma unroll
        for (int j = 0; j < 8; ++j) tile[wl][cb + 8 + j] = b2f((u16)v1[j]);
    }
    __syncthreads();
    const int cl = t >> 2, w16 = (t & 3) * 16;
    float* dst = out + (((size_t)(b * 512 + c0 + cl)) * 64 + h) * 64 + w16;
#pragma unroll
    for (int j = 0; j < 4; ++j) {
        float4 v;
        v.x = tile[w16 + j * 4 + 0][cl];
        v.y = tile[w16 + j * 4 + 1][cl];
        v.z = tile[w16 + j * 4 + 2][cl];
        v.w = tile[w16 + j * 4 + 3][cl];
        *(float4*)(dst + j * 4) = v;
    }
}

// ---------------------------------------------------------------------------
extern "C" void kernel_launch(void* const* d_in, const int* in_sizes, int n_in,
                              void* d_out, int out_size, void* d_ws, size_t ws_size,
                              hipStream_t stream)
{
    (void)in_sizes; (void)n_in; (void)out_size; (void)ws_size;
    const float* x   = (const float*)d_in[0];
    const float* ph  = (const float*)d_in[1];
    const float* pw  = (const float*)d_in[2];
    const float* wq  = (const float*)d_in[3];
    const float* wkv = (const float*)d_in[4];
    const float* wo  = (const float*)d_in[5];
    const float* wob = (const float*)d_in[6];

    char* ws = (char*)d_ws;
    u16* yA  = (u16*)(ws);                  //  32 MB: tokens x 512 bf16
    u16* yB  = (u16*)(ws + 33554432);       //  32 MB
    u16* QKV = (u16*)(ws + 67108864);       //  96 MB: tokens x 1536 bf16 [q|k|v]
    u16* wT  = (u16*)(ws + 167772160);      //  16 MB: transposed weights bf16
    float* out = (float*)d_out;

    embed_kernel<<<dim3(8, 64, 8), 256, 0, stream>>>(x, ph, pw, yA);
    wtrans_kernel<<<dim3(8, 16, 24), 256, 0, stream>>>(wq, wkv, wo, wT);

    u16* yin = yA;
    u16* yout = yB;
    for (int l = 0; l < 4; ++l) {
        for (int axis = 0; axis < 2; ++axis) {
            const u16* wTla = wT + (size_t)(l * 2 + axis) * 2048 * 512;
            const float* bias = wob + (size_t)(l * 2 + axis) * 512;
            // QKV projection: (32768 x 512) @ (512 x 1536)
            gemm_bt<0><<<dim3(256, 12), 256, 0, stream>>>(yin, 512, wTla, nullptr, QKV, 1536);
            // attention along H (axis 0) or W (axis 1)
            int bstr = (axis == 0) ? 1 : 64;
            int tstr = (axis == 0) ? 64 : 1;
            attn_kernel<<<dim3(512), 256, 0, stream>>>(QKV, bstr, tstr);
            // output projection (+bias); axis 1 accumulates onto axis 0 in-place
            const u16* woT = wTla + 512 * 512 + 1024 * 512;
            if (axis == 0)
                gemm_bt<1><<<dim3(256, 4), 256, 0, stream>>>(QKV, 1536, woT, bias, yout, 512);
            else
                gemm_bt<2><<<dim3(256, 4), 256, 0, stream>>>(QKV, 1536, woT, bias, yout, 512);
        }
        u16* tmp = yin; yin = yout; yout = tmp;
    }
    untrans_kernel<<<dim3(8, 64, 8), 256, 0, stream>>>(yin, out);
}

// Round 2
// 1232.545 us; speedup vs baseline: 1.0414x; 1.0414x over previous
//
#include <hip/hip_runtime.h>
#include <stdint.h>

// ---------------------------------------------------------------------------
// SpatialAggregator: axial attention, B=8 C=512 H=W=64, DEPTH=4, HEADS=8
// Staged pipeline, bf16 MFMA (16x16x32), fp32 accumulate.
// ---------------------------------------------------------------------------

typedef __attribute__((ext_vector_type(8))) short bf16x8;
typedef __attribute__((ext_vector_type(4))) float f32x4;
typedef unsigned short u16;
typedef unsigned int u32;

#define MFMA16(a, b, c) __builtin_amdgcn_mfma_f32_16x16x32_bf16((a), (b), (c), 0, 0, 0)

__device__ __forceinline__ float b2f(u16 h) {
    u32 u = ((u32)h) << 16;
    float f;
    __builtin_memcpy(&f, &u, 4);
    return f;
}
__device__ __forceinline__ u16 f2b(float f) {
    u32 u;
    __builtin_memcpy(&u, &f, 4);
    u32 r = (u + 0x7fffu + ((u >> 16) & 1u)) >> 16;   // RNE
    return (u16)r;
}

#define GLD_LDS16(g, l)                                                        \
    __builtin_amdgcn_global_load_lds(                                          \
        (const __attribute__((address_space(1))) void*)(g),                    \
        (__attribute__((address_space(3))) void*)(l), 16, 0, 0)

// ---------------------------------------------------------------------------
// embed: x (B,C,H,W) f32 + pos_h (C,H) + pos_w (C,W) -> y (B,H,W,C) bf16
// ---------------------------------------------------------------------------
__global__ __launch_bounds__(256) void embed_kernel(
    const float* __restrict__ x, const float* __restrict__ ph,
    const float* __restrict__ pw, u16* __restrict__ y)
{
    __shared__ float tile[64][65];
    const int c0 = blockIdx.x * 64, h = blockIdx.y, b = blockIdx.z;
    const int t = threadIdx.x;
#pragma unroll
    for (int i = 0; i < 4; ++i) {
        int cl = (t >> 4) + i * 16;
        int w4 = (t & 15) * 4;
        const float* src = x + (((size_t)(b * 512 + c0 + cl)) * 64 + h) * 64 + w4;
        float4 v = *(const float4*)src;
        float p = ph[(c0 + cl) * 64 + h];
        tile[cl][w4 + 0] = v.x + p + pw[(c0 + cl) * 64 + w4 + 0];
        tile[cl][w4 + 1] = v.y + p + pw[(c0 + cl) * 64 + w4 + 1];
        tile[cl][w4 + 2] = v.z + p + pw[(c0 + cl) * 64 + w4 + 2];
        tile[cl][w4 + 3] = v.w + p + pw[(c0 + cl) * 64 + w4 + 3];
    }
    __syncthreads();
    const int wl = t >> 2, cb = (t & 3) * 16;
    bf16x8 o0, o1;
#pragma unroll
    for (int j = 0; j < 8; ++j) o0[j] = (short)f2b(tile[cb + j][wl]);
#pragma unroll
    for (int j = 0; j < 8; ++j) o1[j] = (short)f2b(tile[cb + 8 + j][wl]);
    u16* dst = y + (((size_t)(b * 64 + h) * 64 + wl) * 512 + c0 + cb);
    *(bf16x8*)dst = o0;
    *(bf16x8*)(dst + 8) = o1;
}

// ---------------------------------------------------------------------------
// weight transpose: W[k][n] f32 -> WT[n][k] bf16, all 24 matrices.
// ---------------------------------------------------------------------------
__global__ __launch_bounds__(256) void wtrans_kernel(
    const float* __restrict__ wq, const float* __restrict__ wkv,
    const float* __restrict__ wo, u16* __restrict__ wT)
{
    const int mid = blockIdx.z;
    const int l = mid / 6, rest = mid % 6, axis = rest / 3, which = rest % 3;
    const size_t la = (size_t)(l * 2 + axis);
    const float* src;
    int N;
    size_t doff;
    if (which == 0)      { src = wq  + la * 512 * 512;  N = 512;  doff = la * (2048 * 512); }
    else if (which == 1) { src = wkv + la * 512 * 1024; N = 1024; doff = la * (2048 * 512) + 512 * 512; }
    else                 { src = wo  + la * 512 * 512;  N = 512;  doff = la * (2048 * 512) + 512 * 512 + 1024 * 512; }
    const int n0 = blockIdx.y * 64;
    if (n0 >= N) return;
    const int k0 = blockIdx.x * 64;
    __shared__ float tile[64][65];
    const int t = threadIdx.x;
#pragma unroll
    for (int i = 0; i < 4; ++i) {
        int kl = (t >> 4) + i * 16;
        int n4 = (t & 15) * 4;
        float4 v = *(const float4*)(src + (size_t)(k0 + kl) * N + n0 + n4);
        tile[kl][n4 + 0] = v.x; tile[kl][n4 + 1] = v.y;
        tile[kl][n4 + 2] = v.z; tile[kl][n4 + 3] = v.w;
    }
    __syncthreads();
    const int nl = t >> 2, kb = (t & 3) * 16;
    bf16x8 o0, o1;
#pragma unroll
    for (int j = 0; j < 8; ++j) o0[j] = (short)f2b(tile[kb + j][nl]);
#pragma unroll
    for (int j = 0; j < 8; ++j) o1[j] = (short)f2b(tile[kb + 8 + j][nl]);
    u16* dst = wT + doff + (size_t)(n0 + nl) * 512 + k0 + kb;
    *(bf16x8*)dst = o0;
    *(bf16x8*)(dst + 8) = o1;
}

// ---------------------------------------------------------------------------
// GEMM: C[M=32768, N] = A[M,512] * WT[N,512]^T (+bias) (+in-place add) -> bf16
// 128x128 tile, BK=64, 4 waves of 64x64, mfma 16x16x32 bf16.
// n-fast work order + XCD chunking: 12 (or 4) consecutive work items share one
// 128KB A panel; B (<=1.5MB) stays L2-resident per XCD.
// Epilogue uses swapped-operand MFMA (D rows = n) -> packed 8B C stores.
// MODE: 0=plain, 1=+bias, 2=+bias+inplace add.
// ---------------------------------------------------------------------------
template <int MODE>
__global__ __launch_bounds__(256) void gemm_bt(
    const u16* __restrict__ A, int lda,
    const u16* __restrict__ Bt,
    const float* __restrict__ bias,
    u16* C, int ldc)
{
    __shared__ u16 As[128 * 64];
    __shared__ u16 Bs[128 * 64];
    const int tid = threadIdx.x;
    const int lane = tid & 63;
    const int wv = tid >> 6;
    const int wr = (wv >> 1) * 64, wc = (wv & 1) * 64;
    const int nbx = gridDim.x;                       // n-blocks (fast dim)
    int lin = blockIdx.x + nbx * blockIdx.y;
    int cpx = (nbx * gridDim.y) >> 3;                // nwg % 8 == 0
    int id = (lin & 7) * cpx + (lin >> 3);           // bijective XCD chunks
    const int n0 = (id % nbx) * 128;
    const int m0 = (id / nbx) * 128;
    const int rl = lane >> 3;
    const int cp = lane & 7;
    const int l16 = lane & 15;
    const int g = lane >> 4;
    const int kgrp = g << 3;
    f32x4 acc[4][4] = {};                            // acc[nf][mf], D rows = n

    for (int ks = 0; ks < 512; ks += 64) {
#pragma unroll
        for (int i = 0; i < 4; ++i) {
            int row = wv * 8 + i * 32 + rl;
            int clog = cp ^ (row & 7);
            const u16* src = A + (size_t)(m0 + row) * lda + ks + clog * 8;
            GLD_LDS16(src, As + (wv * 8 + i * 32) * 64);
        }
#pragma unroll
        for (int i = 0; i < 4; ++i) {
            int row = wv * 8 + i * 32 + rl;
            int clog = cp ^ (row & 7);
            const u16* src = Bt + (size_t)(n0 + row) * 512 + ks + clog * 8;
            GLD_LDS16(src, Bs + (wv * 8 + i * 32) * 64);
        }
        __syncthreads();
#pragma unroll
        for (int kk = 0; kk < 2; ++kk) {
            bf16x8 af[4], bfr[4];
            const int kb = (kk * 32 + kgrp) * 2;
#pragma unroll
            for (int mf = 0; mf < 4; ++mf) {
                int row = wr + mf * 16 + l16;
                af[mf] = *(const bf16x8*)((const char*)As + row * 128 + (kb ^ ((row & 7) << 4)));
            }
#pragma unroll
            for (int nf = 0; nf < 4; ++nf) {
                int row = wc + nf * 16 + l16;
                bfr[nf] = *(const bf16x8*)((const char*)Bs + row * 128 + (kb ^ ((row & 7) << 4)));
            }
#pragma unroll
            for (int nf = 0; nf < 4; ++nf)
#pragma unroll
                for (int mf = 0; mf < 4; ++mf)
                    acc[nf][mf] = MFMA16(bfr[nf], af[mf], acc[nf][mf]);
        }
        __syncthreads();
    }

    // epilogue: D rows = n = wc+nf*16+g*4+r (4 consecutive per lane), cols = m
    float bv[4][4];
    if (MODE >= 1) {
#pragma unroll
        for (int nf = 0; nf < 4; ++nf) {
            float4 b4 = *(const float4*)(bias + n0 + wc + nf * 16 + g * 4);
            bv[nf][0] = b4.x; bv[nf][1] = b4.y; bv[nf][2] = b4.z; bv[nf][3] = b4.w;
        }
    }
#pragma unroll
    for (int mf = 0; mf < 4; ++mf) {
        const int m = m0 + wr + mf * 16 + l16;
#pragma unroll
        for (int nf = 0; nf < 4; ++nf) {
            const int n = n0 + wc + nf * 16 + g * 4;
            u16* cptr = C + (size_t)m * ldc + n;
            float v0 = acc[nf][mf][0], v1 = acc[nf][mf][1];
            float v2 = acc[nf][mf][2], v3 = acc[nf][mf][3];
            if (MODE >= 1) { v0 += bv[nf][0]; v1 += bv[nf][1]; v2 += bv[nf][2]; v3 += bv[nf][3]; }
            if (MODE == 2) {
                ushort4 o = *(const ushort4*)cptr;
                v0 += b2f(o.x); v1 += b2f(o.y); v2 += b2f(o.z); v3 += b2f(o.w);
            }
            uint2 pk;
            pk.x = (u32)f2b(v0) | ((u32)f2b(v1) << 16);
            pk.y = (u32)f2b(v2) | ((u32)f2b(v3) << 16);
            *(uint2*)cptr = pk;
        }
    }
}

// ---------------------------------------------------------------------------
// attention: per sequence of 64 tokens, 8 heads.  QKV rows = [q|k|v] (1536).
// One block = one sequence; 4 waves x 2 heads, waves fully independent
// (per-wave s_waitcnt instead of __syncthreads).
// Swapped QK^T (S^T): softmax nearly in-lane (2 shfls per fragment-row).
// P -> LDS via packed ds_write_b64; PV as mfma(V^T, P) -> O^T whose D layout
// packs 4 consecutive e per lane -> 8B output stores into the Q slots.
// Vt swizzle ((e&7)^((e>>3)&7))<<4 makes the scalar transpose writes
// bank-conflict-free (bank = (i^t^cp)<<2 | rl>>1).
// ---------------------------------------------------------------------------
__global__ __launch_bounds__(256) void attn_kernel(u16* QKV, int bstr, int tstr)
{
    __shared__ u16 sm[4][2][64 * 64];   // per wave: [0]=K then P, [1]=V^T
    const int bi = blockIdx.x;
    const int base = (bi >> 6) * 4096 + (bi & 63) * bstr;
    const int tid = threadIdx.x, lane = tid & 63, wv = tid >> 6;
    const int l16 = lane & 15, g = lane >> 4;
    const int kgrp = g << 3;
    const int rl = lane >> 3, cp = lane & 7;
    u16* Kl = (u16*)sm[wv][0];
    u16* Vt = (u16*)sm[wv][1];

    for (int hh = 0; hh < 2; ++hh) {
        const int head = wv + hh * 4;
        const int hoff = head * 64;

        // K -> LDS (pre-swizzled source, linear dest)
#pragma unroll
        for (int i = 0; i < 8; ++i) {
            int row = i * 8 + rl;
            int clog = cp ^ (row & 7);
            const u16* src = QKV + (size_t)(base + row * tstr) * 1536 + 512 + hoff + clog * 8;
            GLD_LDS16(src, Kl + i * 8 * 64);
        }
        // Q fragments (B-operand): rows i, e-contig
        bf16x8 q[4][2];
#pragma unroll
        for (int i_f = 0; i_f < 4; ++i_f)
#pragma unroll
            for (int k2 = 0; k2 < 2; ++k2)
                q[i_f][k2] = *(const bf16x8*)(QKV + (size_t)(base + (i_f * 16 + l16) * tstr) * 1536
                                              + hoff + k2 * 32 + kgrp);
        // V rows -> regs
        bf16x8 vvr[8];
#pragma unroll
        for (int i = 0; i < 8; ++i)
            vvr[i] = *(const bf16x8*)(QKV + (size_t)(base + (i * 8 + rl) * tstr) * 1536
                                      + 1024 + hoff + cp * 8);

        asm volatile("s_waitcnt vmcnt(0)" ::: "memory");
        __builtin_amdgcn_sched_barrier(0);

        // S^T = mfma(K, Q): rows j = j_f*16 + g*4 + r, cols i = i_f*16 + l16
        f32x4 st[4][4] = {};
#pragma unroll
        for (int k2 = 0; k2 < 2; ++k2) {
            bf16x8 kf[4];
            const int kb = (k2 * 32 + kgrp) * 2;
#pragma unroll
            for (int j_f = 0; j_f < 4; ++j_f) {
                int row = j_f * 16 + l16;
                kf[j_f] = *(const bf16x8*)((const char*)Kl + row * 128 + (kb ^ ((row & 7) << 4)));
            }
#pragma unroll
            for (int i_f = 0; i_f < 4; ++i_f)
#pragma unroll
                for (int j_f = 0; j_f < 4; ++j_f)
                    st[i_f][j_f] = MFMA16(kf[j_f], q[i_f][k2], st[i_f][j_f]);
        }

        // V^T -> LDS, conflict-free swizzle
#pragma unroll
        for (int i = 0; i < 8; ++i) {
            int j2 = i * 16 + rl * 2;               // 2*j
#pragma unroll
            for (int t = 0; t < 8; ++t) {
                int e = cp * 8 + t;
                int addr = e * 128 + (j2 ^ (((t ^ cp) & 7) << 4));
                *(u16*)((char*)Vt + addr) = (u16)vvr[i][t];
            }
        }

        // softmax over j per (i_f): 16 in-lane values + 2 shfls; P -> LDS bf16
#pragma unroll
        for (int i_f = 0; i_f < 4; ++i_f) {
            const int irow = i_f * 16 + l16;
            float ev[4][4];
            float mx = -1e30f;
#pragma unroll
            for (int j_f = 0; j_f < 4; ++j_f)
#pragma unroll
                for (int r = 0; r < 4; ++r) {
                    float v = st[i_f][j_f][r] * 0.125f;
                    ev[j_f][r] = v;
                    mx = fmaxf(mx, v);
                }
            mx = fmaxf(mx, __shfl_xor(mx, 16, 64));
            mx = fmaxf(mx, __shfl_xor(mx, 32, 64));
            float sum = 0.f;
#pragma unroll
            for (int j_f = 0; j_f < 4; ++j_f)
#pragma unroll
                for (int r = 0; r < 4; ++r) {
                    float e = __expf(ev[j_f][r] - mx);
                    ev[j_f][r] = e;
                    sum += e;
                }
            sum += __shfl_xor(sum, 16, 64);
            sum += __shfl_xor(sum, 32, 64);
            float inv = __builtin_amdgcn_rcpf(sum);
#pragma unroll
            for (int j_f = 0; j_f < 4; ++j_f) {
                uint2 pk;
                pk.x = (u32)f2b(ev[j_f][0] * inv) | ((u32)f2b(ev[j_f][1] * inv) << 16);
                pk.y = (u32)f2b(ev[j_f][2] * inv) | ((u32)f2b(ev[j_f][3] * inv) << 16);
                int addr = irow * 128 + ((j_f * 32 + g * 8) ^ ((irow & 7) << 4));
                *(uint2*)((char*)Kl + addr) = pk;
            }
        }

        // O^T = mfma(V^T, P): rows e = e_f*16 + g*4 + r, cols i = i_f*16 + l16
        f32x4 of[4][4] = {};
#pragma unroll
        for (int k2 = 0; k2 < 2; ++k2) {
            bf16x8 vf[4], pf[4];
            const int kb = (k2 * 32 + kgrp) * 2;
#pragma unroll
            for (int e_f = 0; e_f < 4; ++e_f) {
                int row = e_f * 16 + l16;
                int sw = ((row & 7) ^ ((row >> 3) & 7)) << 4;
                vf[e_f] = *(const bf16x8*)((const char*)Vt + row * 128 + (kb ^ sw));
            }
#pragma unroll
            for (int i_f = 0; i_f < 4; ++i_f) {
                int row = i_f * 16 + l16;
                pf[i_f] = *(const bf16x8*)((const char*)Kl + row * 128 + (kb ^ ((row & 7) << 4)));
            }
#pragma unroll
            for (int e_f = 0; e_f < 4; ++e_f)
#pragma unroll
                for (int i_f = 0; i_f < 4; ++i_f)
                    of[e_f][i_f] = MFMA16(vf[e_f], pf[i_f], of[e_f][i_f]);
        }

        // store O into the Q slots: per lane token i, 4 consecutive e -> 8B
#pragma unroll
        for (int i_f = 0; i_f < 4; ++i_f) {
            const int i = i_f * 16 + l16;
            u16* orow = QKV + (size_t)(base + i * tstr) * 1536 + hoff + g * 4;
#pragma unroll
            for (int e_f = 0; e_f < 4; ++e_f) {
                uint2 pk;
                pk.x = (u32)f2b(of[e_f][i_f][0]) | ((u32)f2b(of[e_f][i_f][1]) << 16);
                pk.y = (u32)f2b(of[e_f][i_f][2]) | ((u32)f2b(of[e_f][i_f][3]) << 16);
                *(uint2*)(orow + e_f * 16) = pk;
            }
        }
        // per-wave: drain LDS reads before next head's staging overwrites
        asm volatile("s_waitcnt lgkmcnt(0)" ::: "memory");
        __builtin_amdgcn_sched_barrier(0);
    }
}

// ---------------------------------------------------------------------------
// final: y (B,H,W,C) bf16 -> out (B,C,H,W) f32
// ---------------------------------------------------------------------------
__global__ __launch_bounds__(256) void untrans_kernel(
    const u16* __restrict__ y, float* __restrict__ out)
{
    __shared__ float tile[64][65];   // [w][c]
    const int c0 = blockIdx.x * 64, h = blockIdx.y, b = blockIdx.z;
    const int t = threadIdx.x;
    {
        const int wl = t >> 2, cb = (t & 3) * 16;
        const u16* src = y + (((size_t)(b * 64 + h) * 64 + wl) * 512 + c0 + cb);
        bf16x8 v0 = *(const bf16x8*)src;
        bf16x8 v1 = *(const bf16x8*)(src + 8);
#pragma unroll
        for (int j = 0; j < 8; ++j) tile[wl][cb + j] = b2f((u16)v0[j]);
#pragma unroll
        for (int j = 0; j < 8; ++j) tile[wl][cb + 8 + j] = b2f((u16)v1[j]);
    }
    __syncthreads();
    const int cl = t >> 2, w16 = (t & 3) * 16;
    float* dst = out + (((size_t)(b * 512 + c0 + cl)) * 64 + h) * 64 + w16;
#pragma unroll
    for (int j = 0; j < 4; ++j) {
        float4 v;
        v.x = tile[w16 + j * 4 + 0][cl];
        v.y = tile[w16 + j * 4 + 1][cl];
        v.z = tile[w16 + j * 4 + 2][cl];
        v.w = tile[w16 + j * 4 + 3][cl];
        *(float4*)(dst + j * 4) = v;
    }
}

// ---------------------------------------------------------------------------
extern "C" void kernel_launch(void* const* d_in, const int* in_sizes, int n_in,
                              void* d_out, int out_size, void* d_ws, size_t ws_size,
                              hipStream_t stream)
{
    (void)in_sizes; (void)n_in; (void)out_size; (void)ws_size;
    const float* x   = (const float*)d_in[0];
    const float* ph  = (const float*)d_in[1];
    const float* pw  = (const float*)d_in[2];
    const float* wq  = (const float*)d_in[3];
    const float* wkv = (const float*)d_in[4];
    const float* wo  = (const float*)d_in[5];
    const float* wob = (const float*)d_in[6];

    char* ws = (char*)d_ws;
    u16* yA  = (u16*)(ws);                  //  32 MB: tokens x 512 bf16
    u16* yB  = (u16*)(ws + 33554432);       //  32 MB
    u16* QKV = (u16*)(ws + 67108864);       //  96 MB: tokens x 1536 bf16 [q|k|v]
    u16* wT  = (u16*)(ws + 167772160);      //  16 MB: transposed weights bf16
    float* out = (float*)d_out;

    embed_kernel<<<dim3(8, 64, 8), 256, 0, stream>>>(x, ph, pw, yA);
    wtrans_kernel<<<dim3(8, 16, 24), 256, 0, stream>>>(wq, wkv, wo, wT);

    u16* yin = yA;
    u16* yout = yB;
    for (int l = 0; l < 4; ++l) {
        for (int axis = 0; axis < 2; ++axis) {
            const u16* wTla = wT + (size_t)(l * 2 + axis) * 2048 * 512;
            const float* bias = wob + (size_t)(l * 2 + axis) * 512;
            // QKV projection: (32768 x 512) @ (512 x 1536), n-fast grid
            gemm_bt<0><<<dim3(12, 256), 256, 0, stream>>>(yin, 512, wTla, nullptr, QKV, 1536);
            // attention along H (axis 0) or W (axis 1)
            int bstr = (axis == 0) ? 1 : 64;
            int tstr = (axis == 0) ? 64 : 1;
            attn_kernel<<<dim3(512), 256, 0, stream>>>(QKV, bstr, tstr);
            // output projection (+bias); axis 1 accumulates onto axis 0 in-place
            const u16* woT = wTla + 512 * 512 + 1024 * 512;
            if (axis == 0)
                gemm_bt<1><<<dim3(4, 256), 256, 0, stream>>>(QKV, 1536, woT, bias, yout, 512);
            else
                gemm_bt<2><<<dim3(4, 256), 256, 0, stream>>>(QKV, 1536, woT, bias, yout, 512);
        }
        u16* tmp = yin; yin = yout; yout = tmp;
    }
    untrans_kernel<<<dim3(8, 64, 8), 256, 0, stream>>>(yin, out);
}

// Round 3
// 1180.639 us; speedup vs baseline: 1.0872x; 1.0440x over previous
//
#include <hip/hip_runtime.h>
#include <stdint.h>

// ---------------------------------------------------------------------------
// SpatialAggregator: axial attention, B=8 C=512 H=W=64, DEPTH=4, HEADS=8
// Staged pipeline, bf16 MFMA (16x16x32), fp32 accumulate.
// R3: permuted QKV layout (attn tokens always row-contiguous), wave-per-unit
// attention (4096 independent wave-units, no barriers).
// ---------------------------------------------------------------------------

typedef __attribute__((ext_vector_type(8))) short bf16x8;
typedef __attribute__((ext_vector_type(4))) float f32x4;
typedef unsigned short u16;
typedef unsigned int u32;

#define MFMA16(a, b, c) __builtin_amdgcn_mfma_f32_16x16x32_bf16((a), (b), (c), 0, 0, 0)

__device__ __forceinline__ float b2f(u16 h) {
    u32 u = ((u32)h) << 16;
    float f;
    __builtin_memcpy(&f, &u, 4);
    return f;
}
__device__ __forceinline__ u16 f2b(float f) {
    u32 u;
    __builtin_memcpy(&u, &f, 4);
    u32 r = (u + 0x7fffu + ((u >> 16) & 1u)) >> 16;   // RNE
    return (u16)r;
}

#define GLD_LDS16(g, l)                                                        \
    __builtin_amdgcn_global_load_lds(                                          \
        (const __attribute__((address_space(1))) void*)(g),                    \
        (__attribute__((address_space(3))) void*)(l), 16, 0, 0)

// ---------------------------------------------------------------------------
// embed: x (B,C,H,W) f32 + pos_h (C,H) + pos_w (C,W) -> y (B,H,W,C) bf16
// ---------------------------------------------------------------------------
__global__ __launch_bounds__(256) void embed_kernel(
    const float* __restrict__ x, const float* __restrict__ ph,
    const float* __restrict__ pw, u16* __restrict__ y)
{
    __shared__ float tile[64][65];
    const int c0 = blockIdx.x * 64, h = blockIdx.y, b = blockIdx.z;
    const int t = threadIdx.x;
#pragma unroll
    for (int i = 0; i < 4; ++i) {
        int cl = (t >> 4) + i * 16;
        int w4 = (t & 15) * 4;
        const float* src = x + (((size_t)(b * 512 + c0 + cl)) * 64 + h) * 64 + w4;
        float4 v = *(const float4*)src;
        float p = ph[(c0 + cl) * 64 + h];
        tile[cl][w4 + 0] = v.x + p + pw[(c0 + cl) * 64 + w4 + 0];
        tile[cl][w4 + 1] = v.y + p + pw[(c0 + cl) * 64 + w4 + 1];
        tile[cl][w4 + 2] = v.z + p + pw[(c0 + cl) * 64 + w4 + 2];
        tile[cl][w4 + 3] = v.w + p + pw[(c0 + cl) * 64 + w4 + 3];
    }
    __syncthreads();
    const int wl = t >> 2, cb = (t & 3) * 16;
    bf16x8 o0, o1;
#pragma unroll
    for (int j = 0; j < 8; ++j) o0[j] = (short)f2b(tile[cb + j][wl]);
#pragma unroll
    for (int j = 0; j < 8; ++j) o1[j] = (short)f2b(tile[cb + 8 + j][wl]);
    u16* dst = y + (((size_t)(b * 64 + h) * 64 + wl) * 512 + c0 + cb);
    *(bf16x8*)dst = o0;
    *(bf16x8*)(dst + 8) = o1;
}

// ---------------------------------------------------------------------------
// weight transpose: W[k][n] f32 -> WT[n][k] bf16, all 24 matrices.
// ---------------------------------------------------------------------------
__global__ __launch_bounds__(256) void wtrans_kernel(
    const float* __restrict__ wq, const float* __restrict__ wkv,
    const float* __restrict__ wo, u16* __restrict__ wT)
{
    const int mid = blockIdx.z;
    const int l = mid / 6, rest = mid % 6, axis = rest / 3, which = rest % 3;
    const size_t la = (size_t)(l * 2 + axis);
    const float* src;
    int N;
    size_t doff;
    if (which == 0)      { src = wq  + la * 512 * 512;  N = 512;  doff = la * (2048 * 512); }
    else if (which == 1) { src = wkv + la * 512 * 1024; N = 1024; doff = la * (2048 * 512) + 512 * 512; }
    else                 { src = wo  + la * 512 * 512;  N = 512;  doff = la * (2048 * 512) + 512 * 512 + 1024 * 512; }
    const int n0 = blockIdx.y * 64;
    if (n0 >= N) return;
    const int k0 = blockIdx.x * 64;
    __shared__ float tile[64][65];
    const int t = threadIdx.x;
#pragma unroll
    for (int i = 0; i < 4; ++i) {
        int kl = (t >> 4) + i * 16;
        int n4 = (t & 15) * 4;
        float4 v = *(const float4*)(src + (size_t)(k0 + kl) * N + n0 + n4);
        tile[kl][n4 + 0] = v.x; tile[kl][n4 + 1] = v.y;
        tile[kl][n4 + 2] = v.z; tile[kl][n4 + 3] = v.w;
    }
    __syncthreads();
    const int nl = t >> 2, kb = (t & 3) * 16;
    bf16x8 o0, o1;
#pragma unroll
    for (int j = 0; j < 8; ++j) o0[j] = (short)f2b(tile[kb + j][nl]);
#pragma unroll
    for (int j = 0; j < 8; ++j) o1[j] = (short)f2b(tile[kb + 8 + j][nl]);
    u16* dst = wT + doff + (size_t)(n0 + nl) * 512 + k0 + kb;
    *(bf16x8*)dst = o0;
    *(bf16x8*)(dst + 8) = o1;
}

// ---------------------------------------------------------------------------
// GEMM: C[M=32768, N] = A[M,512] * WT[N,512]^T (+bias) (+in-place add) -> bf16
// 128x128 tile, BK=64, 4 waves of 64x64, mfma 16x16x32 bf16.
// MODE: 0=plain, 1=+bias, 2=+bias+inplace add.
// PERM: epilogue row permutation (b,h,w)<->(b,w,h) — an involution — so the
// attention kernel always sees token-contiguous rows for both axes.
// ---------------------------------------------------------------------------
template <int MODE, int PERM>
__global__ __launch_bounds__(256) void gemm_bt(
    const u16* __restrict__ A, int lda,
    const u16* __restrict__ Bt,
    const float* __restrict__ bias,
    u16* C, int ldc)
{
    __shared__ u16 As[128 * 64];
    __shared__ u16 Bs[128 * 64];
    const int tid = threadIdx.x;
    const int lane = tid & 63;
    const int wv = tid >> 6;
    const int wr = (wv >> 1) * 64, wc = (wv & 1) * 64;
    const int nbx = gridDim.x;                       // n-blocks (fast dim)
    int lin = blockIdx.x + nbx * blockIdx.y;
    int cpx = (nbx * gridDim.y) >> 3;                // nwg % 8 == 0
    int id = (lin & 7) * cpx + (lin >> 3);           // bijective XCD chunks
    const int n0 = (id % nbx) * 128;
    const int m0 = (id / nbx) * 128;
    const int rl = lane >> 3;
    const int cp = lane & 7;
    const int l16 = lane & 15;
    const int g = lane >> 4;
    const int kgrp = g << 3;
    f32x4 acc[4][4] = {};                            // acc[nf][mf], D rows = n

    for (int ks = 0; ks < 512; ks += 64) {
#pragma unroll
        for (int i = 0; i < 4; ++i) {
            int row = wv * 8 + i * 32 + rl;
            int clog = cp ^ (row & 7);
            const u16* src = A + (size_t)(m0 + row) * lda + ks + clog * 8;
            GLD_LDS16(src, As + (wv * 8 + i * 32) * 64);
        }
#pragma unroll
        for (int i = 0; i < 4; ++i) {
            int row = wv * 8 + i * 32 + rl;
            int clog = cp ^ (row & 7);
            const u16* src = Bt + (size_t)(n0 + row) * 512 + ks + clog * 8;
            GLD_LDS16(src, Bs + (wv * 8 + i * 32) * 64);
        }
        __syncthreads();
#pragma unroll
        for (int kk = 0; kk < 2; ++kk) {
            bf16x8 af[4], bfr[4];
            const int kb = (kk * 32 + kgrp) * 2;
#pragma unroll
            for (int mf = 0; mf < 4; ++mf) {
                int row = wr + mf * 16 + l16;
                af[mf] = *(const bf16x8*)((const char*)As + row * 128 + (kb ^ ((row & 7) << 4)));
            }
#pragma unroll
            for (int nf = 0; nf < 4; ++nf) {
                int row = wc + nf * 16 + l16;
                bfr[nf] = *(const bf16x8*)((const char*)Bs + row * 128 + (kb ^ ((row & 7) << 4)));
            }
#pragma unroll
            for (int nf = 0; nf < 4; ++nf)
#pragma unroll
                for (int mf = 0; mf < 4; ++mf)
                    acc[nf][mf] = MFMA16(bfr[nf], af[mf], acc[nf][mf]);
        }
        __syncthreads();
    }

    // epilogue: D rows = n = wc+nf*16+g*4+r (4 consecutive per lane), cols = m
    float bv[4][4];
    if (MODE >= 1) {
#pragma unroll
        for (int nf = 0; nf < 4; ++nf) {
            float4 b4 = *(const float4*)(bias + n0 + wc + nf * 16 + g * 4);
            bv[nf][0] = b4.x; bv[nf][1] = b4.y; bv[nf][2] = b4.z; bv[nf][3] = b4.w;
        }
    }
#pragma unroll
    for (int mf = 0; mf < 4; ++mf) {
        const int m = m0 + wr + mf * 16 + l16;
        const int mp = PERM ? ((m & ~4095) | ((m & 63) << 6) | ((m >> 6) & 63)) : m;
        u16* crow = C + (size_t)mp * ldc;
#pragma unroll
        for (int nf = 0; nf < 4; ++nf) {
            const int n = n0 + wc + nf * 16 + g * 4;
            u16* cptr = crow + n;
            float v0 = acc[nf][mf][0], v1 = acc[nf][mf][1];
            float v2 = acc[nf][mf][2], v3 = acc[nf][mf][3];
            if (MODE >= 1) { v0 += bv[nf][0]; v1 += bv[nf][1]; v2 += bv[nf][2]; v3 += bv[nf][3]; }
            if (MODE == 2) {
                ushort4 o = *(const ushort4*)cptr;
                v0 += b2f(o.x); v1 += b2f(o.y); v2 += b2f(o.z); v3 += b2f(o.w);
            }
            uint2 pk;
            pk.x = (u32)f2b(v0) | ((u32)f2b(v1) << 16);
            pk.y = (u32)f2b(v2) | ((u32)f2b(v3) << 16);
            *(uint2*)cptr = pk;
        }
    }
}

// ---------------------------------------------------------------------------
// attention: QKV rows are token-contiguous per sequence (64 rows of 1536).
// One WAVE per (seq, head) unit: 4096 units = 1024 blocks x 4 waves, fully
// independent (no barriers; per-wave s_waitcnt only).
// Swapped QK^T (S^T): softmax nearly in-lane; P -> LDS packed; PV as
// mfma(V^T, P) -> O^T -> 8B stores into the Q slots.
// ---------------------------------------------------------------------------
__global__ __launch_bounds__(256) void attn_kernel(u16* QKV)
{
    __shared__ u16 sm[4][2][64 * 64];   // per wave: [0]=K then P, [1]=V^T
    const int tid = threadIdx.x, lane = tid & 63, wv = tid >> 6;
    const int unit = blockIdx.x * 4 + wv;        // 4096 = 512 seq x 8 heads
    const int base = (unit >> 3) * 64;           // first token row
    const int hoff = (unit & 7) * 64;            // head column offset
    const int l16 = lane & 15, g = lane >> 4;
    const int kgrp = g << 3;
    const int rl = lane >> 3, cp = lane & 7;
    u16* Kl = (u16*)sm[wv][0];
    u16* Vt = (u16*)sm[wv][1];

    // K -> LDS (pre-swizzled source, linear dest)
#pragma unroll
    for (int i = 0; i < 8; ++i) {
        int row = i * 8 + rl;
        int clog = cp ^ (row & 7);
        const u16* src = QKV + (size_t)(base + row) * 1536 + 512 + hoff + clog * 8;
        GLD_LDS16(src, Kl + i * 8 * 64);
    }
    // Q fragments (B-operand): rows i, e-contig
    bf16x8 q[4][2];
#pragma unroll
    for (int i_f = 0; i_f < 4; ++i_f)
#pragma unroll
        for (int k2 = 0; k2 < 2; ++k2)
            q[i_f][k2] = *(const bf16x8*)(QKV + (size_t)(base + i_f * 16 + l16) * 1536
                                          + hoff + k2 * 32 + kgrp);
    // V rows -> regs
    bf16x8 vvr[8];
#pragma unroll
    for (int i = 0; i < 8; ++i)
        vvr[i] = *(const bf16x8*)(QKV + (size_t)(base + i * 8 + rl) * 1536
                                  + 1024 + hoff + cp * 8);

    asm volatile("s_waitcnt vmcnt(0)" ::: "memory");
    __builtin_amdgcn_sched_barrier(0);

    // S^T = mfma(K, Q): rows j = j_f*16 + g*4 + r, cols i = i_f*16 + l16
    f32x4 st[4][4] = {};
#pragma unroll
    for (int k2 = 0; k2 < 2; ++k2) {
        bf16x8 kf[4];
        const int kb = (k2 * 32 + kgrp) * 2;
#pragma unroll
        for (int j_f = 0; j_f < 4; ++j_f) {
            int row = j_f * 16 + l16;
            kf[j_f] = *(const bf16x8*)((const char*)Kl + row * 128 + (kb ^ ((row & 7) << 4)));
        }
#pragma unroll
        for (int i_f = 0; i_f < 4; ++i_f)
#pragma unroll
            for (int j_f = 0; j_f < 4; ++j_f)
                st[i_f][j_f] = MFMA16(kf[j_f], q[i_f][k2], st[i_f][j_f]);
    }

    // V^T -> LDS, conflict-free swizzle
#pragma unroll
    for (int i = 0; i < 8; ++i) {
        int j2 = i * 16 + rl * 2;               // 2*j
#pragma unroll
        for (int t = 0; t < 8; ++t) {
            int e = cp * 8 + t;
            int addr = e * 128 + (j2 ^ (((t ^ cp) & 7) << 4));
            *(u16*)((char*)Vt + addr) = (u16)vvr[i][t];
        }
    }

    // softmax over j per (i_f): 16 in-lane values + 2 shfls; P -> LDS bf16
#pragma unroll
    for (int i_f = 0; i_f < 4; ++i_f) {
        const int irow = i_f * 16 + l16;
        float ev[4][4];
        float mx = -1e30f;
#pragma unroll
        for (int j_f = 0; j_f < 4; ++j_f)
#pragma unroll
            for (int r = 0; r < 4; ++r) {
                float v = st[i_f][j_f][r] * 0.125f;
                ev[j_f][r] = v;
                mx = fmaxf(mx, v);
            }
        mx = fmaxf(mx, __shfl_xor(mx, 16, 64));
        mx = fmaxf(mx, __shfl_xor(mx, 32, 64));
        float sum = 0.f;
#pragma unroll
        for (int j_f = 0; j_f < 4; ++j_f)
#pragma unroll
            for (int r = 0; r < 4; ++r) {
                float e = __expf(ev[j_f][r] - mx);
                ev[j_f][r] = e;
                sum += e;
            }
        sum += __shfl_xor(sum, 16, 64);
        sum += __shfl_xor(sum, 32, 64);
        float inv = __builtin_amdgcn_rcpf(sum);
#pragma unroll
        for (int j_f = 0; j_f < 4; ++j_f) {
            uint2 pk;
            pk.x = (u32)f2b(ev[j_f][0] * inv) | ((u32)f2b(ev[j_f][1] * inv) << 16);
            pk.y = (u32)f2b(ev[j_f][2] * inv) | ((u32)f2b(ev[j_f][3] * inv) << 16);
            int addr = irow * 128 + ((j_f * 32 + g * 8) ^ ((irow & 7) << 4));
            *(uint2*)((char*)Kl + addr) = pk;
        }
    }

    // O^T = mfma(V^T, P): rows e = e_f*16 + g*4 + r, cols i = i_f*16 + l16
    f32x4 of[4][4] = {};
#pragma unroll
    for (int k2 = 0; k2 < 2; ++k2) {
        bf16x8 vf[4], pf[4];
        const int kb = (k2 * 32 + kgrp) * 2;
#pragma unroll
        for (int e_f = 0; e_f < 4; ++e_f) {
            int row = e_f * 16 + l16;
            int sw = ((row & 7) ^ ((row >> 3) & 7)) << 4;
            vf[e_f] = *(const bf16x8*)((const char*)Vt + row * 128 + (kb ^ sw));
        }
#pragma unroll
        for (int i_f = 0; i_f < 4; ++i_f) {
            int row = i_f * 16 + l16;
            pf[i_f] = *(const bf16x8*)((const char*)Kl + row * 128 + (kb ^ ((row & 7) << 4)));
        }
#pragma unroll
        for (int e_f = 0; e_f < 4; ++e_f)
#pragma unroll
            for (int i_f = 0; i_f < 4; ++i_f)
                of[e_f][i_f] = MFMA16(vf[e_f], pf[i_f], of[e_f][i_f]);
    }

    // store O into the Q slots: per lane token i, 4 consecutive e -> 8B
#pragma unroll
    for (int i_f = 0; i_f < 4; ++i_f) {
        const int i = i_f * 16 + l16;
        u16* orow = QKV + (size_t)(base + i) * 1536 + hoff + g * 4;
#pragma unroll
        for (int e_f = 0; e_f < 4; ++e_f) {
            uint2 pk;
            pk.x = (u32)f2b(of[e_f][i_f][0]) | ((u32)f2b(of[e_f][i_f][1]) << 16);
            pk.y = (u32)f2b(of[e_f][i_f][2]) | ((u32)f2b(of[e_f][i_f][3]) << 16);
            *(uint2*)(orow + e_f * 16) = pk;
        }
    }
}

// ---------------------------------------------------------------------------
// final: y (B,H,W,C) bf16 -> out (B,C,H,W) f32
// ---------------------------------------------------------------------------
__global__ __launch_bounds__(256) void untrans_kernel(
    const u16* __restrict__ y, float* __restrict__ out)
{
    __shared__ float tile[64][65];   // [w][c]
    const int c0 = blockIdx.x * 64, h = blockIdx.y, b = blockIdx.z;
    const int t = threadIdx.x;
    {
        const int wl = t >> 2, cb = (t & 3) * 16;
        const u16* src = y + (((size_t)(b * 64 + h) * 64 + wl) * 512 + c0 + cb);
        bf16x8 v0 = *(const bf16x8*)src;
        bf16x8 v1 = *(const bf16x8*)(src + 8);
#pragma unroll
        for (int j = 0; j < 8; ++j) tile[wl][cb + j] = b2f((u16)v0[j]);
#pragma unroll
        for (int j = 0; j < 8; ++j) tile[wl][cb + 8 + j] = b2f((u16)v1[j]);
    }
    __syncthreads();
    const int cl = t >> 2, w16 = (t & 3) * 16;
    float* dst = out + (((size_t)(b * 512 + c0 + cl)) * 64 + h) * 64 + w16;
#pragma unroll
    for (int j = 0; j < 4; ++j) {
        float4 v;
        v.x = tile[w16 + j * 4 + 0][cl];
        v.y = tile[w16 + j * 4 + 1][cl];
        v.z = tile[w16 + j * 4 + 2][cl];
        v.w = tile[w16 + j * 4 + 3][cl];
        *(float4*)(dst + j * 4) = v;
    }
}

// ---------------------------------------------------------------------------
extern "C" void kernel_launch(void* const* d_in, const int* in_sizes, int n_in,
                              void* d_out, int out_size, void* d_ws, size_t ws_size,
                              hipStream_t stream)
{
    (void)in_sizes; (void)n_in; (void)out_size; (void)ws_size;
    const float* x   = (const float*)d_in[0];
    const float* ph  = (const float*)d_in[1];
    const float* pw  = (const float*)d_in[2];
    const float* wq  = (const float*)d_in[3];
    const float* wkv = (const float*)d_in[4];
    const float* wo  = (const float*)d_in[5];
    const float* wob = (const float*)d_in[6];

    char* ws = (char*)d_ws;
    u16* yA  = (u16*)(ws);                  //  32 MB: tokens x 512 bf16
    u16* yB  = (u16*)(ws + 33554432);       //  32 MB
    u16* QKV = (u16*)(ws + 67108864);       //  96 MB: tokens x 1536 bf16 [q|k|v]
    u16* wT  = (u16*)(ws + 167772160);      //  16 MB: transposed weights bf16
    float* out = (float*)d_out;

    embed_kernel<<<dim3(8, 64, 8), 256, 0, stream>>>(x, ph, pw, yA);
    wtrans_kernel<<<dim3(8, 16, 24), 256, 0, stream>>>(wq, wkv, wo, wT);

    u16* yin = yA;
    u16* yout = yB;
    for (int l = 0; l < 4; ++l) {
        for (int axis = 0; axis < 2; ++axis) {
            const u16* wTla = wT + (size_t)(l * 2 + axis) * 2048 * 512;
            const float* bias = wob + (size_t)(l * 2 + axis) * 512;
            const u16* woT = wTla + 512 * 512 + 1024 * 512;
            // QKV projection: (32768 x 512) @ (512 x 1536), n-fast grid.
            // axis 0 writes rows permuted (b,w,h) so tokens are contiguous.
            if (axis == 0)
                gemm_bt<0, 1><<<dim3(12, 256), 256, 0, stream>>>(yin, 512, wTla, nullptr, QKV, 1536);
            else
                gemm_bt<0, 0><<<dim3(12, 256), 256, 0, stream>>>(yin, 512, wTla, nullptr, QKV, 1536);
            // attention: 4096 independent wave-units
            attn_kernel<<<dim3(1024), 256, 0, stream>>>(QKV);
            // output projection (+bias); axis 0 un-permutes rows in epilogue;
            // axis 1 accumulates onto axis 0's canonical output in-place.
            if (axis == 0)
                gemm_bt<1, 1><<<dim3(4, 256), 256, 0, stream>>>(QKV, 1536, woT, bias, yout, 512);
            else
                gemm_bt<2, 0><<<dim3(4, 256), 256, 0, stream>>>(QKV, 1536, woT, bias, yout, 512);
        }
        u16* tmp = yin; yin = yout; yout = tmp;
    }
    untrans_kernel<<<dim3(8, 64, 8), 256, 0, stream>>>(yin, out);
}

// Round 4
// 1075.812 us; speedup vs baseline: 1.1932x; 1.0974x over previous
//
#include <hip/hip_runtime.h>
#include <stdint.h>

// ---------------------------------------------------------------------------
// SpatialAggregator: axial attention, B=8 C=512 H=W=64, DEPTH=4, HEADS=8
// R4: 256x256-tile 8-wave GEMM with counted-vmcnt double-buffered pipeline
// (T3/T4), T2 LDS swizzle, T5 setprio.  Attention as in R3.
// ---------------------------------------------------------------------------

typedef __attribute__((ext_vector_type(8))) short bf16x8;
typedef __attribute__((ext_vector_type(4))) float f32x4;
typedef unsigned short u16;
typedef unsigned int u32;

#define MFMA16(a, b, c) __builtin_amdgcn_mfma_f32_16x16x32_bf16((a), (b), (c), 0, 0, 0)

__device__ __forceinline__ float b2f(u16 h) {
    u32 u = ((u32)h) << 16;
    float f;
    __builtin_memcpy(&f, &u, 4);
    return f;
}
__device__ __forceinline__ u16 f2b(float f) {
    u32 u;
    __builtin_memcpy(&u, &f, 4);
    u32 r = (u + 0x7fffu + ((u >> 16) & 1u)) >> 16;   // RNE
    return (u16)r;
}

#define GLD_LDS16(g, l)                                                        \
    __builtin_amdgcn_global_load_lds(                                          \
        (const __attribute__((address_space(1))) void*)(g),                    \
        (__attribute__((address_space(3))) void*)(l), 16, 0, 0)

// ---------------------------------------------------------------------------
// embed: x (B,C,H,W) f32 + pos_h (C,H) + pos_w (C,W) -> y (B,H,W,C) bf16
// ---------------------------------------------------------------------------
__global__ __launch_bounds__(256) void embed_kernel(
    const float* __restrict__ x, const float* __restrict__ ph,
    const float* __restrict__ pw, u16* __restrict__ y)
{
    __shared__ float tile[64][65];
    const int c0 = blockIdx.x * 64, h = blockIdx.y, b = blockIdx.z;
    const int t = threadIdx.x;
#pragma unroll
    for (int i = 0; i < 4; ++i) {
        int cl = (t >> 4) + i * 16;
        int w4 = (t & 15) * 4;
        const float* src = x + (((size_t)(b * 512 + c0 + cl)) * 64 + h) * 64 + w4;
        float4 v = *(const float4*)src;
        float p = ph[(c0 + cl) * 64 + h];
        tile[cl][w4 + 0] = v.x + p + pw[(c0 + cl) * 64 + w4 + 0];
        tile[cl][w4 + 1] = v.y + p + pw[(c0 + cl) * 64 + w4 + 1];
        tile[cl][w4 + 2] = v.z + p + pw[(c0 + cl) * 64 + w4 + 2];
        tile[cl][w4 + 3] = v.w + p + pw[(c0 + cl) * 64 + w4 + 3];
    }
    __syncthreads();
    const int wl = t >> 2, cb = (t & 3) * 16;
    bf16x8 o0, o1;
#pragma unroll
    for (int j = 0; j < 8; ++j) o0[j] = (short)f2b(tile[cb + j][wl]);
#pragma unroll
    for (int j = 0; j < 8; ++j) o1[j] = (short)f2b(tile[cb + 8 + j][wl]);
    u16* dst = y + (((size_t)(b * 64 + h) * 64 + wl) * 512 + c0 + cb);
    *(bf16x8*)dst = o0;
    *(bf16x8*)(dst + 8) = o1;
}

// ---------------------------------------------------------------------------
// weight transpose: W[k][n] f32 -> WT[n][k] bf16, all 24 matrices.
// ---------------------------------------------------------------------------
__global__ __launch_bounds__(256) void wtrans_kernel(
    const float* __restrict__ wq, const float* __restrict__ wkv,
    const float* __restrict__ wo, u16* __restrict__ wT)
{
    const int mid = blockIdx.z;
    const int l = mid / 6, rest = mid % 6, axis = rest / 3, which = rest % 3;
    const size_t la = (size_t)(l * 2 + axis);
    const float* src;
    int N;
    size_t doff;
    if (which == 0)      { src = wq  + la * 512 * 512;  N = 512;  doff = la * (2048 * 512); }
    else if (which == 1) { src = wkv + la * 512 * 1024; N = 1024; doff = la * (2048 * 512) + 512 * 512; }
    else                 { src = wo  + la * 512 * 512;  N = 512;  doff = la * (2048 * 512) + 512 * 512 + 1024 * 512; }
    const int n0 = blockIdx.y * 64;
    if (n0 >= N) return;
    const int k0 = blockIdx.x * 64;
    __shared__ float tile[64][65];
    const int t = threadIdx.x;
#pragma unroll
    for (int i = 0; i < 4; ++i) {
        int kl = (t >> 4) + i * 16;
        int n4 = (t & 15) * 4;
        float4 v = *(const float4*)(src + (size_t)(k0 + kl) * N + n0 + n4);
        tile[kl][n4 + 0] = v.x; tile[kl][n4 + 1] = v.y;
        tile[kl][n4 + 2] = v.z; tile[kl][n4 + 3] = v.w;
    }
    __syncthreads();
    const int nl = t >> 2, kb = (t & 3) * 16;
    bf16x8 o0, o1;
#pragma unroll
    for (int j = 0; j < 8; ++j) o0[j] = (short)f2b(tile[kb + j][nl]);
#pragma unroll
    for (int j = 0; j < 8; ++j) o1[j] = (short)f2b(tile[kb + 8 + j][nl]);
    u16* dst = wT + doff + (size_t)(n0 + nl) * 512 + k0 + kb;
    *(bf16x8*)dst = o0;
    *(bf16x8*)(dst + 8) = o1;
}

// ---------------------------------------------------------------------------
// GEMM 256x256 tile, BK=64, 8 waves (2M x 4N) of 128x64 output each.
// Counted-vmcnt double-buffered K-pipeline:
//   per iter: issue 8 gload_lds for tile t+1 -> other buf; vmcnt(8) (tile t's
//   loads retire, 8 stay in flight); s_barrier; 4 MFMA phases (setprio);
//   s_barrier (all reads done before next iter's stages may overwrite).
// Raw s_barrier (not __syncthreads) so the compiler cannot reinsert vmcnt(0).
// MODE: 0=plain, 1=+bias, 2=+bias+inplace add.  PERM: (b,h,w)<->(b,w,h) rows.
// ---------------------------------------------------------------------------
template <int MODE, int PERM>
__global__ __launch_bounds__(512, 2) void gemm256(
    const u16* __restrict__ A, int lda,
    const u16* __restrict__ Bt,
    const float* __restrict__ bias,
    u16* C, int ldc)
{
    __shared__ u16 As[2][256 * 64];
    __shared__ u16 Bs[2][256 * 64];
    const int tid = threadIdx.x, lane = tid & 63, wid = tid >> 6;
    const int wm = wid >> 2, wn = wid & 3;          // 2 x 4 wave grid
    int lin = blockIdx.x + gridDim.x * blockIdx.y;  // n-fast
    int cpx = (gridDim.x * gridDim.y) >> 3;         // nwg % 8 == 0
    int id = (lin & 7) * cpx + (lin >> 3);          // bijective XCD chunks
    const int n0 = (id % gridDim.x) * 256;
    const int m0 = (id / gridDim.x) * 256;
    const int rl = lane >> 3, cp = lane & 7, l16 = lane & 15, g = lane >> 4;
    const int kgrp = g << 3;

    f32x4 acc[4][8] = {};                           // [nf][mf], D rows = n

    // stage K-tile (element offset ks) into buffer b: 8 issues/thread
#define STAGE(b, ks)                                                           \
    {                                                                          \
        _Pragma("unroll")                                                      \
        for (int j = 0; j < 4; ++j) {                                          \
            int grp = wid + 8 * j;                                             \
            int row = grp * 8 + rl;                                            \
            const u16* s = A + (size_t)(m0 + row) * lda + (ks) + (cp ^ (row & 7)) * 8; \
            GLD_LDS16(s, As[b] + grp * 512);                                   \
        }                                                                      \
        _Pragma("unroll")                                                      \
        for (int j = 0; j < 4; ++j) {                                          \
            int grp = wid + 8 * j;                                             \
            int row = grp * 8 + rl;                                            \
            const u16* s = Bt + (size_t)(n0 + row) * 512 + (ks) + (cp ^ (row & 7)) * 8; \
            GLD_LDS16(s, Bs[b] + grp * 512);                                   \
        }                                                                      \
    }

#define FRAG(base, row, kk)                                                    \
    (*(const bf16x8*)((const char*)(base) + (row) * 128 +                      \
                      (((kk) * 64 + g * 16) ^ (((row) & 7) << 4))))

    STAGE(0, 0);

    for (int t = 0; t < 8; ++t) {
        const int cb = t & 1;
        if (t < 7) STAGE(cb ^ 1, (t + 1) * 64);
        __builtin_amdgcn_sched_barrier(0);
        if (t < 7) { asm volatile("s_waitcnt vmcnt(8)" ::: "memory"); }
        else       { asm volatile("s_waitcnt vmcnt(0)" ::: "memory"); }
        __builtin_amdgcn_s_barrier();
        __builtin_amdgcn_sched_barrier(0);

        const u16* cA = As[cb];
        const u16* cB = Bs[cb];
        bf16x8 bl[2][2], bh[2][2], af[4][2];

        // phase 1: quadrant (m-lo, n-lo)
#pragma unroll
        for (int nf = 0; nf < 2; ++nf)
#pragma unroll
            for (int kk = 0; kk < 2; ++kk)
                bl[nf][kk] = FRAG(cB, wn * 64 + nf * 16 + l16, kk);
#pragma unroll
        for (int mf = 0; mf < 4; ++mf)
#pragma unroll
            for (int kk = 0; kk < 2; ++kk)
                af[mf][kk] = FRAG(cA, wm * 128 + mf * 16 + l16, kk);
        __builtin_amdgcn_s_setprio(1);
#pragma unroll
        for (int kk = 0; kk < 2; ++kk)
#pragma unroll
            for (int nf = 0; nf < 2; ++nf)
#pragma unroll
                for (int mf = 0; mf < 4; ++mf)
                    acc[nf][mf] = MFMA16(bl[nf][kk], af[mf][kk], acc[nf][mf]);
        __builtin_amdgcn_s_setprio(0);

        // phase 2: quadrant (m-lo, n-hi)
#pragma unroll
        for (int nf = 0; nf < 2; ++nf)
#pragma unroll
            for (int kk = 0; kk < 2; ++kk)
                bh[nf][kk] = FRAG(cB, wn * 64 + 32 + nf * 16 + l16, kk);
        __builtin_amdgcn_s_setprio(1);
#pragma unroll
        for (int kk = 0; kk < 2; ++kk)
#pragma unroll
            for (int nf = 0; nf < 2; ++nf)
#pragma unroll
                for (int mf = 0; mf < 4; ++mf)
                    acc[2 + nf][mf] = MFMA16(bh[nf][kk], af[mf][kk], acc[2 + nf][mf]);
        __builtin_amdgcn_s_setprio(0);

        // phase 3: quadrant (m-hi, n-hi)
#pragma unroll
        for (int mf = 0; mf < 4; ++mf)
#pragma unroll
            for (int kk = 0; kk < 2; ++kk)
                af[mf][kk] = FRAG(cA, wm * 128 + 64 + mf * 16 + l16, kk);
        __builtin_amdgcn_s_setprio(1);
#pragma unroll
        for (int kk = 0; kk < 2; ++kk)
#pragma unroll
            for (int nf = 0; nf < 2; ++nf)
#pragma unroll
                for (int mf = 0; mf < 4; ++mf)
                    acc[2 + nf][4 + mf] = MFMA16(bh[nf][kk], af[mf][kk], acc[2 + nf][4 + mf]);
        __builtin_amdgcn_s_setprio(0);

        // phase 4: quadrant (m-hi, n-lo)  (bl held in regs since phase 1)
        __builtin_amdgcn_s_setprio(1);
#pragma unroll
        for (int kk = 0; kk < 2; ++kk)
#pragma unroll
            for (int nf = 0; nf < 2; ++nf)
#pragma unroll
                for (int mf = 0; mf < 4; ++mf)
                    acc[nf][4 + mf] = MFMA16(bl[nf][kk], af[mf][kk], acc[nf][4 + mf]);
        __builtin_amdgcn_s_setprio(0);

        __builtin_amdgcn_sched_barrier(0);
        __builtin_amdgcn_s_barrier();    // all reads of buf cb done
        __builtin_amdgcn_sched_barrier(0);
    }

    // epilogue: D rows = n = n0+wn*64+nf*16+g*4+r (4 consecutive per lane)
    float bv[4][4];
    if (MODE >= 1) {
#pragma unroll
        for (int nf = 0; nf < 4; ++nf) {
            float4 b4 = *(const float4*)(bias + n0 + wn * 64 + nf * 16 + g * 4);
            bv[nf][0] = b4.x; bv[nf][1] = b4.y; bv[nf][2] = b4.z; bv[nf][3] = b4.w;
        }
    }
#pragma unroll
    for (int mf = 0; mf < 8; ++mf) {
        const int m = m0 + wm * 128 + mf * 16 + l16;
        const int mp = PERM ? ((m & ~4095) | ((m & 63) << 6) | ((m >> 6) & 63)) : m;
        u16* crow = C + (size_t)mp * ldc;
#pragma unroll
        for (int nf = 0; nf < 4; ++nf) {
            const int n = n0 + wn * 64 + nf * 16 + g * 4;
            u16* cptr = crow + n;
            float v0 = acc[nf][mf][0], v1 = acc[nf][mf][1];
            float v2 = acc[nf][mf][2], v3 = acc[nf][mf][3];
            if (MODE >= 1) { v0 += bv[nf][0]; v1 += bv[nf][1]; v2 += bv[nf][2]; v3 += bv[nf][3]; }
            if (MODE == 2) {
                ushort4 o = *(const ushort4*)cptr;
                v0 += b2f(o.x); v1 += b2f(o.y); v2 += b2f(o.z); v3 += b2f(o.w);
            }
            uint2 pk;
            pk.x = (u32)f2b(v0) | ((u32)f2b(v1) << 16);
            pk.y = (u32)f2b(v2) | ((u32)f2b(v3) << 16);
            *(uint2*)cptr = pk;
        }
    }
#undef STAGE
#undef FRAG
}

// ---------------------------------------------------------------------------
// attention: QKV rows are token-contiguous per sequence (64 rows of 1536).
// One WAVE per (seq, head) unit: 4096 units = 1024 blocks x 4 waves.
// ---------------------------------------------------------------------------
__global__ __launch_bounds__(256) void attn_kernel(u16* QKV)
{
    __shared__ u16 sm[4][2][64 * 64];   // per wave: [0]=K then P, [1]=V^T
    const int tid = threadIdx.x, lane = tid & 63, wv = tid >> 6;
    const int unit = blockIdx.x * 4 + wv;        // 4096 = 512 seq x 8 heads
    const int base = (unit >> 3) * 64;           // first token row
    const int hoff = (unit & 7) * 64;            // head column offset
    const int l16 = lane & 15, g = lane >> 4;
    const int kgrp = g << 3;
    const int rl = lane >> 3, cp = lane & 7;
    u16* Kl = (u16*)sm[wv][0];
    u16* Vt = (u16*)sm[wv][1];

    // K -> LDS (pre-swizzled source, linear dest)
#pragma unroll
    for (int i = 0; i < 8; ++i) {
        int row = i * 8 + rl;
        int clog = cp ^ (row & 7);
        const u16* src = QKV + (size_t)(base + row) * 1536 + 512 + hoff + clog * 8;
        GLD_LDS16(src, Kl + i * 8 * 64);
    }
    // Q fragments (B-operand): rows i, e-contig
    bf16x8 q[4][2];
#pragma unroll
    for (int i_f = 0; i_f < 4; ++i_f)
#pragma unroll
        for (int k2 = 0; k2 < 2; ++k2)
            q[i_f][k2] = *(const bf16x8*)(QKV + (size_t)(base + i_f * 16 + l16) * 1536
                                          + hoff + k2 * 32 + kgrp);
    // V rows -> regs
    bf16x8 vvr[8];
#pragma unroll
    for (int i = 0; i < 8; ++i)
        vvr[i] = *(const bf16x8*)(QKV + (size_t)(base + i * 8 + rl) * 1536
                                  + 1024 + hoff + cp * 8);

    asm volatile("s_waitcnt vmcnt(0)" ::: "memory");
    __builtin_amdgcn_sched_barrier(0);

    // S^T = mfma(K, Q): rows j = j_f*16 + g*4 + r, cols i = i_f*16 + l16
    f32x4 st[4][4] = {};
#pragma unroll
    for (int k2 = 0; k2 < 2; ++k2) {
        bf16x8 kf[4];
        const int kb = (k2 * 32 + kgrp) * 2;
#pragma unroll
        for (int j_f = 0; j_f < 4; ++j_f) {
            int row = j_f * 16 + l16;
            kf[j_f] = *(const bf16x8*)((const char*)Kl + row * 128 + (kb ^ ((row & 7) << 4)));
        }
#pragma unroll
        for (int i_f = 0; i_f < 4; ++i_f)
#pragma unroll
            for (int j_f = 0; j_f < 4; ++j_f)
                st[i_f][j_f] = MFMA16(kf[j_f], q[i_f][k2], st[i_f][j_f]);
    }

    // V^T -> LDS, conflict-free swizzle
#pragma unroll
    for (int i = 0; i < 8; ++i) {
        int j2 = i * 16 + rl * 2;               // 2*j
#pragma unroll
        for (int t = 0; t < 8; ++t) {
            int e = cp * 8 + t;
            int addr = e * 128 + (j2 ^ (((t ^ cp) & 7) << 4));
            *(u16*)((char*)Vt + addr) = (u16)vvr[i][t];
        }
    }

    // softmax over j per (i_f): 16 in-lane values + 2 shfls; P -> LDS bf16
#pragma unroll
    for (int i_f = 0; i_f < 4; ++i_f) {
        const int irow = i_f * 16 + l16;
        float ev[4][4];
        float mx = -1e30f;
#pragma unroll
        for (int j_f = 0; j_f < 4; ++j_f)
#pragma unroll
            for (int r = 0; r < 4; ++r) {
                float v = st[i_f][j_f][r] * 0.125f;
                ev[j_f][r] = v;
                mx = fmaxf(mx, v);
            }
        mx = fmaxf(mx, __shfl_xor(mx, 16, 64));
        mx = fmaxf(mx, __shfl_xor(mx, 32, 64));
        float sum = 0.f;
#pragma unroll
        for (int j_f = 0; j_f < 4; ++j_f)
#pragma unroll
            for (int r = 0; r < 4; ++r) {
                float e = __expf(ev[j_f][r] - mx);
                ev[j_f][r] = e;
                sum += e;
            }
        sum += __shfl_xor(sum, 16, 64);
        sum += __shfl_xor(sum, 32, 64);
        float inv = __builtin_amdgcn_rcpf(sum);
#pragma unroll
        for (int j_f = 0; j_f < 4; ++j_f) {
            uint2 pk;
            pk.x = (u32)f2b(ev[j_f][0] * inv) | ((u32)f2b(ev[j_f][1] * inv) << 16);
            pk.y = (u32)f2b(ev[j_f][2] * inv) | ((u32)f2b(ev[j_f][3] * inv) << 16);
            int addr = irow * 128 + ((j_f * 32 + g * 8) ^ ((irow & 7) << 4));
            *(uint2*)((char*)Kl + addr) = pk;
        }
    }

    // O^T = mfma(V^T, P): rows e = e_f*16 + g*4 + r, cols i = i_f*16 + l16
    f32x4 of[4][4] = {};
#pragma unroll
    for (int k2 = 0; k2 < 2; ++k2) {
        bf16x8 vf[4], pf[4];
        const int kb = (k2 * 32 + kgrp) * 2;
#pragma unroll
        for (int e_f = 0; e_f < 4; ++e_f) {
            int row = e_f * 16 + l16;
            int sw = ((row & 7) ^ ((row >> 3) & 7)) << 4;
            vf[e_f] = *(const bf16x8*)((const char*)Vt + row * 128 + (kb ^ sw));
        }
#pragma unroll
        for (int i_f = 0; i_f < 4; ++i_f) {
            int row = i_f * 16 + l16;
            pf[i_f] = *(const bf16x8*)((const char*)Kl + row * 128 + (kb ^ ((row & 7) << 4)));
        }
#pragma unroll
        for (int e_f = 0; e_f < 4; ++e_f)
#pragma unroll
            for (int i_f = 0; i_f < 4; ++i_f)
                of[e_f][i_f] = MFMA16(vf[e_f], pf[i_f], of[e_f][i_f]);
    }

    // store O into the Q slots: per lane token i, 4 consecutive e -> 8B
#pragma unroll
    for (int i_f = 0; i_f < 4; ++i_f) {
        const int i = i_f * 16 + l16;
        u16* orow = QKV + (size_t)(base + i) * 1536 + hoff + g * 4;
#pragma unroll
        for (int e_f = 0; e_f < 4; ++e_f) {
            uint2 pk;
            pk.x = (u32)f2b(of[e_f][i_f][0]) | ((u32)f2b(of[e_f][i_f][1]) << 16);
            pk.y = (u32)f2b(of[e_f][i_f][2]) | ((u32)f2b(of[e_f][i_f][3]) << 16);
            *(uint2*)(orow + e_f * 16) = pk;
        }
    }
}

// ---------------------------------------------------------------------------
// final: y (B,H,W,C) bf16 -> out (B,C,H,W) f32
// ---------------------------------------------------------------------------
__global__ __launch_bounds__(256) void untrans_kernel(
    const u16* __restrict__ y, float* __restrict__ out)
{
    __shared__ float tile[64][65];   // [w][c]
    const int c0 = blockIdx.x * 64, h = blockIdx.y, b = blockIdx.z;
    const int t = threadIdx.x;
    {
        const int wl = t >> 2, cb = (t & 3) * 16;
        const u16* src = y + (((size_t)(b * 64 + h) * 64 + wl) * 512 + c0 + cb);
        bf16x8 v0 = *(const bf16x8*)src;
        bf16x8 v1 = *(const bf16x8*)(src + 8);
#pragma unroll
        for (int j = 0; j < 8; ++j) tile[wl][cb + j] = b2f((u16)v0[j]);
#pragma unroll
        for (int j = 0; j < 8; ++j) tile[wl][cb + 8 + j] = b2f((u16)v1[j]);
    }
    __syncthreads();
    const int cl = t >> 2, w16 = (t & 3) * 16;
    float* dst = out + (((size_t)(b * 512 + c0 + cl)) * 64 + h) * 64 + w16;
#pragma unroll
    for (int j = 0; j < 4; ++j) {
        float4 v;
        v.x = tile[w16 + j * 4 + 0][cl];
        v.y = tile[w16 + j * 4 + 1][cl];
        v.z = tile[w16 + j * 4 + 2][cl];
        v.w = tile[w16 + j * 4 + 3][cl];
        *(float4*)(dst + j * 4) = v;
    }
}

// ---------------------------------------------------------------------------
extern "C" void kernel_launch(void* const* d_in, const int* in_sizes, int n_in,
                              void* d_out, int out_size, void* d_ws, size_t ws_size,
                              hipStream_t stream)
{
    (void)in_sizes; (void)n_in; (void)out_size; (void)ws_size;
    const float* x   = (const float*)d_in[0];
    const float* ph  = (const float*)d_in[1];
    const float* pw  = (const float*)d_in[2];
    const float* wq  = (const float*)d_in[3];
    const float* wkv = (const float*)d_in[4];
    const float* wo  = (const float*)d_in[5];
    const float* wob = (const float*)d_in[6];

    char* ws = (char*)d_ws;
    u16* yA  = (u16*)(ws);                  //  32 MB: tokens x 512 bf16
    u16* yB  = (u16*)(ws + 33554432);       //  32 MB
    u16* QKV = (u16*)(ws + 67108864);       //  96 MB: tokens x 1536 bf16 [q|k|v]
    u16* wT  = (u16*)(ws + 167772160);      //  16 MB: transposed weights bf16
    float* out = (float*)d_out;

    embed_kernel<<<dim3(8, 64, 8), 256, 0, stream>>>(x, ph, pw, yA);
    wtrans_kernel<<<dim3(8, 16, 24), 256, 0, stream>>>(wq, wkv, wo, wT);

    u16* yin = yA;
    u16* yout = yB;
    for (int l = 0; l < 4; ++l) {
        for (int axis = 0; axis < 2; ++axis) {
            const u16* wTla = wT + (size_t)(l * 2 + axis) * 2048 * 512;
            const float* bias = wob + (size_t)(l * 2 + axis) * 512;
            const u16* woT = wTla + 512 * 512 + 1024 * 512;
            // QKV projection: (32768 x 512) @ (512 x 1536), 256^2 tiles, n-fast
            if (axis == 0)
                gemm256<0, 1><<<dim3(6, 128), 512, 0, stream>>>(yin, 512, wTla, nullptr, QKV, 1536);
            else
                gemm256<0, 0><<<dim3(6, 128), 512, 0, stream>>>(yin, 512, wTla, nullptr, QKV, 1536);
            // attention: 4096 independent wave-units
            attn_kernel<<<dim3(1024), 256, 0, stream>>>(QKV);
            // output projection (+bias); axis 0 un-permutes rows in epilogue;
            // axis 1 accumulates onto axis 0's canonical output in-place.
            if (axis == 0)
                gemm256<1, 1><<<dim3(2, 128), 512, 0, stream>>>(QKV, 1536, woT, bias, yout, 512);
            else
                gemm256<2, 0><<<dim3(2, 128), 512, 0, stream>>>(QKV, 1536, woT, bias, yout, 512);
        }
        u16* tmp = yin; yin = yout; yout = tmp;
    }
    untrans_kernel<<<dim3(8, 64, 8), 256, 0, stream>>>(yin, out);
}